// Round 1
// baseline (2132.845 us; speedup 1.0000x reference)
//
#include <hip/hip_runtime.h>
#include <cstdint>

#define K_DIM 4096
#define M_TOK 4096
#define VOCAB_N 32000
#define CCHUNKS 500  // 32000/64 column-chunks of 64

typedef short s16x8 __attribute__((ext_vector_type(8)));
typedef float f32x4 __attribute__((ext_vector_type(4)));

__device__ __forceinline__ unsigned short f2bf(float f) {
  unsigned int u = __builtin_bit_cast(unsigned int, f);
  u += 0x7fffu + ((u >> 16) & 1u);  // RNE
  return (unsigned short)(u >> 16);
}

// fp32 [rows][4096] row-major  ->  blocked bf16: 16B unit(kb, r) at dst[kb*dst_stride + r],
// unit holds elements k = kb*8 .. kb*8+7 of row r. Coalesced reads, LDS transpose, coalesced writes.
__global__ __launch_bounds__(256) void convert_blk(const float* __restrict__ src,
                                                   uint4* __restrict__ dst,
                                                   int dst_stride) {
  __shared__ unsigned short lds[64 * 68];  // 64 rows x 64 elems, padded to 68
  const int tid = threadIdx.x;
  const int r0 = blockIdx.x * 64;
  const int k0 = blockIdx.y * 64;
#pragma unroll
  for (int it = 0; it < 4; ++it) {
    int idx = it * 256 + tid;
    int rl = idx >> 4, kv = idx & 15;
    const float4 v = *(const float4*)(src + (size_t)(r0 + rl) * K_DIM + k0 + kv * 4);
    ushort4 b;
    b.x = f2bf(v.x); b.y = f2bf(v.y); b.z = f2bf(v.z); b.w = f2bf(v.w);
    *(ushort4*)(&lds[rl * 68 + kv * 4]) = b;
  }
  __syncthreads();
#pragma unroll
  for (int it = 0; it < 2; ++it) {
    int u = it * 256 + tid;
    int kb = u >> 6, rl = u & 63;
    ushort4 a = *(const ushort4*)(&lds[rl * 68 + kb * 8]);
    ushort4 b = *(const ushort4*)(&lds[rl * 68 + kb * 8 + 4]);
    uint4 val;
    val.x = (unsigned)a.x | ((unsigned)a.y << 16);
    val.y = (unsigned)a.z | ((unsigned)a.w << 16);
    val.z = (unsigned)b.x | ((unsigned)b.y << 16);
    val.w = (unsigned)b.z | ((unsigned)b.w << 16);
    dst[(size_t)(k0 / 8 + kb) * dst_stride + r0 + rl] = val;
  }
}

__device__ __forceinline__ void gl_lds16(const void* g, void* l) {
  __builtin_amdgcn_global_load_lds((const __attribute__((address_space(1))) void*)g,
                                   (__attribute__((address_space(3))) void*)l,
                                   16, 0, 0);
}

// 128x128 logits tile, K=4096, bf16 MFMA 16x16x32; epilogue: bias + per-64-col (max,sumexp)
// partials written to lse_part[row*500 + cc]. No logits to HBM.
__global__ __launch_bounds__(256, 2) void gemm_lse(const uint4* __restrict__ Ablk,
                                                   const uint4* __restrict__ Wblk,
                                                   const float* __restrict__ bias,
                                                   float2* __restrict__ lse_part,
                                                   int col0, int wstride) {
  __shared__ uint4 ldsA[1024];  // 16KB: unit(kb_local 0..7, m 0..127) = ldsA[kb*128+m]
  __shared__ uint4 ldsB[1024];
  const int tid = threadIdx.x;
  const int wave = tid >> 6, lane = tid & 63;
  const int l15 = lane & 15, quad = lane >> 4;
  const int wm = wave >> 1, wn = wave & 1;
  const int tile_n = blockIdx.x, tile_m = blockIdx.y;

  f32x4 acc[4][4] = {};

  const uint4* ga[4];
  const uint4* gb[4];
  uint4* la[4];
  uint4* lb[4];
#pragma unroll
  for (int t = 0; t < 4; ++t) {
    int u = wave * 4 + t;          // 16 x 1KiB staging instructions, 4 per wave
    int kb = u >> 1, m0 = (u & 1) << 6;
    ga[t] = Ablk + ((size_t)kb * 4096 + tile_m * 128 + m0 + lane);
    gb[t] = Wblk + ((size_t)kb * wstride + tile_n * 128 + m0 + lane);
    la[t] = ldsA + u * 64;
    lb[t] = ldsB + u * 64;
  }

  for (int kt = 0; kt < 64; ++kt) {
#pragma unroll
    for (int t = 0; t < 4; ++t) {
      gl_lds16(ga[t], la[t]);
      gl_lds16(gb[t], lb[t]);
      ga[t] += 8 * 4096;
      gb[t] += 8 * wstride;
    }
    __syncthreads();  // compiler drains vmcnt before s_barrier -> LDS valid
#pragma unroll
    for (int kk = 0; kk < 2; ++kk) {
      const int kb0 = kk * 4 + quad;
      const uint4* pA = ldsA + kb0 * 128 + wm * 64 + l15;
      const uint4* pB = ldsB + kb0 * 128 + wn * 64 + l15;
      s16x8 af[4], bfr[4];
#pragma unroll
      for (int i = 0; i < 4; ++i) af[i] = __builtin_bit_cast(s16x8, pA[i * 16]);
#pragma unroll
      for (int j = 0; j < 4; ++j) bfr[j] = __builtin_bit_cast(s16x8, pB[j * 16]);
#pragma unroll
      for (int i = 0; i < 4; ++i)
#pragma unroll
        for (int j = 0; j < 4; ++j)
          acc[i][j] = __builtin_amdgcn_mfma_f32_16x16x32_bf16(af[i], bfr[j], acc[i][j], 0, 0, 0);
    }
    __syncthreads();  // all reads done before next stage overwrites
  }

  // ---- epilogue: per-row (max, sumexp) over this wave's 64 columns ----
  const int colbase = col0 + tile_n * 128 + wn * 64 + l15;
  float bcol[4];
#pragma unroll
  for (int j = 0; j < 4; ++j) bcol[j] = bias[colbase + j * 16];
  const int cc = (col0 >> 6) + tile_n * 2 + wn;
#pragma unroll
  for (int i = 0; i < 4; ++i) {
#pragma unroll
    for (int r = 0; r < 4; ++r) {
      float v0 = acc[i][0][r] + bcol[0];
      float v1 = acc[i][1][r] + bcol[1];
      float v2 = acc[i][2][r] + bcol[2];
      float v3 = acc[i][3][r] + bcol[3];
      float mx = fmaxf(fmaxf(v0, v1), fmaxf(v2, v3));
      float s = __expf(v0 - mx) + __expf(v1 - mx) + __expf(v2 - mx) + __expf(v3 - mx);
#pragma unroll
      for (int msk = 1; msk <= 8; msk <<= 1) {  // reduce across the 16-lane quad group
        float om = __shfl_xor(mx, msk);
        float os = __shfl_xor(s, msk);
        float M = fmaxf(mx, om);
        s = s * __expf(mx - M) + os * __expf(om - M);
        mx = M;
      }
      if (l15 == i * 4 + r) {  // one writer lane per (row-in-quad)
        int row = tile_m * 128 + wm * 64 + i * 16 + quad * 4 + r;
        lse_part[(size_t)row * CCHUNKS + cc] = make_float2(mx, s);
      }
    }
  }
}

// one wave per token row: merge 500 partials -> lse; exact fp32 target dot; atomic reduce
__global__ __launch_bounds__(256) void finalize(const float2* __restrict__ lse_part,
                                                const float* __restrict__ X,
                                                const float* __restrict__ W,
                                                const float* __restrict__ bias,
                                                const int* __restrict__ target,
                                                float* __restrict__ accum) {
  const int wave = threadIdx.x >> 6, lane = threadIdx.x & 63;
  const int row = blockIdx.x * 4 + wave;
  float m = -__builtin_inff(), s = 0.f;
  for (int c = lane; c < CCHUNKS; c += 64) {
    float2 p = lse_part[(size_t)row * CCHUNKS + c];
    float M = fmaxf(m, p.x);
    s = s * __expf(m - M) + p.y * __expf(p.x - M);
    m = M;
  }
#pragma unroll
  for (int msk = 1; msk < 64; msk <<= 1) {
    float om = __shfl_xor(m, msk);
    float os = __shfl_xor(s, msk);
    float M = fmaxf(m, om);
    s = s * __expf(m - M) + os * __expf(om - M);
    m = M;
  }
  float lse = m + __logf(s);

  int t = target[row];
  bool valid = (t != -100);
  int st = valid ? t : 0;
  float dot = 0.f;
  const float4* x4 = (const float4*)(X + (size_t)row * K_DIM);
  const float4* w4 = (const float4*)(W + (size_t)st * K_DIM);
  for (int k = lane; k < K_DIM / 4; k += 64) {
    float4 a = x4[k], b = w4[k];
    dot = fmaf(a.x, b.x, fmaf(a.y, b.y, fmaf(a.z, b.z, fmaf(a.w, b.w, dot))));
  }
#pragma unroll
  for (int msk = 1; msk < 64; msk <<= 1) dot += __shfl_xor(dot, msk);
  if (lane == 0 && valid) {
    atomicAdd(&accum[0], lse - (dot + bias[t]));
    atomicAdd(&accum[1], 1.0f);
  }
}

__global__ void final_div(const float* __restrict__ accum, float* __restrict__ out) {
  out[0] = accum[0] / fmaxf(accum[1], 1.0f);
}

extern "C" void kernel_launch(void* const* d_in, const int* in_sizes, int n_in,
                              void* d_out, int out_size, void* d_ws, size_t ws_size,
                              hipStream_t stream) {
  (void)in_sizes; (void)n_in; (void)out_size;
  const float* W    = (const float*)d_in[0];  // lin_weight [32000][4096]
  const float* X    = (const float*)d_in[1];  // _input     [4096][4096]
  const int*   tgt  = (const int*)d_in[2];    // target     [4096]
  const float* bias = (const float*)d_in[5];  // bias       [32000]
  // d_in[3], d_in[4] (ref model) unused: BETA == 0.

  char* ws = (char*)d_ws;
  const size_t OFF_LSE = 0;                     // 4096*500*8 = 16,384,000 B
  const size_t OFF_A   = 16384256;              // A_bf16 blocked: 33,554,432 B
  const size_t OFF_W   = OFF_A + 33554432ull;   // W chunk blocked
  int CHUNK = 4096;                             // vocab rows per chunk (shrink if ws small)
  while (CHUNK > 512 && OFF_W + (size_t)CHUNK * 8192 + 256 > ws_size) CHUNK >>= 1;
  const size_t OFF_ACC = OFF_W + (size_t)CHUNK * 8192;

  float2* lse_part = (float2*)(ws + OFF_LSE);
  uint4*  Ablk     = (uint4*)(ws + OFF_A);
  uint4*  Wblk     = (uint4*)(ws + OFF_W);
  float*  accum    = (float*)(ws + OFF_ACC);

  hipMemsetAsync(accum, 0, 16, stream);
  convert_blk<<<dim3(M_TOK / 64, K_DIM / 64), 256, 0, stream>>>(X, Ablk, 4096);
  for (int c0 = 0; c0 < VOCAB_N; c0 += CHUNK) {
    int nrows = VOCAB_N - c0;
    if (nrows > CHUNK) nrows = CHUNK;  // tails (3328/1280/256) are multiples of 128
    convert_blk<<<dim3(nrows / 64, K_DIM / 64), 256, 0, stream>>>(W + (size_t)c0 * K_DIM, Wblk, CHUNK);
    gemm_lse<<<dim3(nrows / 128, M_TOK / 128), 256, 0, stream>>>(Ablk, Wblk, bias, lse_part, c0, CHUNK);
  }
  finalize<<<M_TOK / 4, 256, 0, stream>>>(lse_part, X, W, bias, tgt, accum);
  final_div<<<1, 1, 0, stream>>>(accum, (float*)d_out);
}